// Round 6
// baseline (599.012 us; speedup 1.0000x reference)
//
#include <hip/hip_runtime.h>
#include <cstdint>
#include <cstddef>

// ---------------------------------------------------------------------------
// Problem constants (B=4096, DIN=DOUT=1024, E=8, K=4)
// ---------------------------------------------------------------------------
#define NB 4096
#define ND 1024

typedef __attribute__((ext_vector_type(8))) short short8v;
typedef __attribute__((ext_vector_type(4))) short short4v;
typedef __attribute__((ext_vector_type(4))) float float4v;

__device__ __forceinline__ unsigned short f2bf(float x){
  union{float f; unsigned u;} v; v.f = x;
  unsigned r = v.u + 0x7FFFu + ((v.u >> 16) & 1u);  // RNE
  return (unsigned short)(r >> 16);
}
__device__ __forceinline__ float bf2f(unsigned short h){
  union{unsigned u; float f;} v; v.u = ((unsigned)h) << 16; return v.f;
}

// fast activations (err ~1e-7, well under bf16 eps)
__device__ __forceinline__ float fast_tanh(float x){
  float xc = fminf(fmaxf(x, -15.f), 15.f);
  float e2 = __expf(2.f * xc);
  return 1.f - 2.f / (e2 + 1.f);
}
__device__ __forceinline__ float fast_silu(float x){
  return x / (1.f + __expf(-x));
}
__device__ __forceinline__ float fast_gelu(float x){
  // exact gelu with Abramowitz-Stegun 7.1.26 erf (|err| <= 1.5e-7)
  float a = fabsf(x) * 0.70710678118654752f;
  float t = 1.f / (1.f + 0.3275911f * a);
  float poly = t * (0.254829592f + t * (-0.284496736f + t * (1.421413741f +
               t * (-1.453152027f + t * 1.061405429f))));
  float erf = 1.f - poly * __expf(-a * a);
  erf = (x < 0.f) ? -erf : erf;
  return 0.5f * x * (1.f + erf);
}

typedef const __attribute__((address_space(1))) unsigned int* gas_ptr;
typedef __attribute__((address_space(3))) unsigned int* las_ptr;

__device__ __forceinline__ void gload_lds16(const void* g, void* l){
  __builtin_amdgcn_global_load_lds((gas_ptr)g, (las_ptr)l, 16, 0, 0);
}

struct GemmArgs {
  const unsigned short* A;     // bf16 [M][lda]
  const unsigned short* A2;    // xlo (gate only)
  const unsigned short* Bt;    // bf16 [N][K]
  int lda;
  int K;
  const float* bias;           // [N]
  unsigned short* H;           // KIND0 dest (cols 0..7167)
  unsigned short* eoc;         // KIND0 conv dest [2][4096][1024]
  unsigned short* eolin;       // KIND1 dest [6][4096][1024]
  float* outsh;                // KIND1 shared dest (d_out)
  float* T;                    // KIND2 dest [2][4096][512] raw partials
};

// ---------------------------------------------------------------------------
// 256x256xBK=64 fine-phased bf16 MFMA GEMM (8 waves 2Mx4N, counted vmcnt(8),
// XOR-swizzled LDS, per-phase barriers + setprio). KIND 0 = L1, KIND 1 = L2.
// Schedule per K-tile:
//   stage(t+1) all 8 loads -> vmcnt(8) [tile t landed, 8 in flight] -> barrier
//   4 phases: {ds_read quadrant (+B at q0); barrier; lgkmcnt(0)+sched_barrier;
//              setprio(1); 16 MFMA; setprio(0); barrier}
// ---------------------------------------------------------------------------
#define STAGE_HALF(gb, grow0, ldm, kel, ldsbase, h)                          \
  { _Pragma("unroll")                                                         \
    for (int s_ = 0; s_ < 2; s_++){                                           \
      int r_ = (h)*128 + s_*64 + srow_in;                                     \
      gload_lds16((gb) + (size_t)((grow0) + r_) * (ldm) + (kel) + scol,       \
                  (ldsbase) + (h)*16384 + s_*8192 + tid*16);                  \
    } }

template<int KIND>
__global__ __launch_bounds__(512, 2) void k_gemm8(GemmArgs g){
  __shared__ __align__(16) char sm[131072];
  const int tid  = threadIdx.x;
  const int lane = tid & 63;
  const int wid  = tid >> 6;
  const int wr = wid >> 2;     // 0..1
  const int wc = wid & 3;      // 0..3
  const int fr = lane & 15;
  const int q16 = lane >> 4;   // 0..3

  // XCD-aware swizzle (gridDim.x % 8 == 0 for both kinds)
  const int chunk = gridDim.x >> 3;
  const int wg = (blockIdx.x & 7) * chunk + (blockIdx.x >> 3);
  const int bx = wg & 15;      // 16 M-tiles (M=4096)
  const int by = wg >> 4;
  const int m0 = bx * 256;
  const int n0 = by * 256;
  const int K   = g.K;
  const int lda = g.lda;
  const int region = n0 >> 10;

  const unsigned short* Ag = g.A + (KIND == 1 ? (size_t)region * 1024 : 0);
  const unsigned short* Bg = g.Bt;

  // fragment LDS byte offsets (row stride 128B; XOR swizzle by fr&7)
  int axor[2];
  axor[0] = (q16 * 16) ^ ((fr & 7) << 4);
  axor[1] = (64 + q16 * 16) ^ ((fr & 7) << 4);
  int arow[8], brow[4];
  #pragma unroll
  for (int mi = 0; mi < 8; mi++) arow[mi] = (wr*128 + mi*16 + fr) * 128;
  #pragma unroll
  for (int ni = 0; ni < 4; ni++) brow[ni] = (wc*64 + ni*16 + fr) * 128;

  float4v acc[8][4];
  #pragma unroll
  for (int i = 0; i < 8; i++)
    #pragma unroll
    for (int j = 0; j < 4; j++) acc[i][j] = (float4v){0.f, 0.f, 0.f, 0.f};

  // staging coords: linear LDS dest (tid*16), inverse-swizzled global col
  const int srow_in = tid >> 3;                           // row within sweep
  const int scol = (((tid & 7) * 16) ^ ((srow_in & 7) << 4)) >> 1;

  // prologue: tile 0 -> buffer 0
  STAGE_HALF(Ag, m0, lda, 0, sm, 0);
  STAGE_HALF(Ag, m0, lda, 0, sm, 1);
  STAGE_HALF(Bg, n0, K, 0, sm + 32768, 0);
  STAGE_HALF(Bg, n0, K, 0, sm + 32768, 1);

  const int NT = K >> 6;
  for (int t = 0; t < NT; t++){
    char* Ab = sm + (size_t)(t & 1) * 65536;
    char* Bb = Ab + 32768;
    char* An = sm + (size_t)((t & 1) ^ 1) * 65536;
    char* Bn = An + 32768;
    const int k1 = (t + 1) << 6;
    if (t + 1 < NT){
      STAGE_HALF(Ag, m0, lda, k1, An, 0);
      STAGE_HALF(Ag, m0, lda, k1, An, 1);
      STAGE_HALF(Bg, n0, K, k1, Bn, 0);
      STAGE_HALF(Bg, n0, K, k1, Bn, 1);
      asm volatile("s_waitcnt vmcnt(8)" ::: "memory");  // tile t landed; 8 in flight
    } else {
      asm volatile("s_waitcnt vmcnt(0)" ::: "memory");
    }
    __builtin_amdgcn_s_barrier();      // tile t ready for all waves

    short8v bfr0[4], bfr1[4];
    #pragma unroll
    for (int q = 0; q < 4; q++){
      // ---- phase q: ds_read issue ----
      if (q == 0){
        #pragma unroll
        for (int ni = 0; ni < 4; ni++){
          bfr0[ni] = *(const short8v*)(Bb + brow[ni] + axor[0]);
          bfr1[ni] = *(const short8v*)(Bb + brow[ni] + axor[1]);
        }
      }
      short8v a00 = *(const short8v*)(Ab + arow[2*q]     + axor[0]);
      short8v a01 = *(const short8v*)(Ab + arow[2*q]     + axor[1]);
      short8v a10 = *(const short8v*)(Ab + arow[2*q + 1] + axor[0]);
      short8v a11 = *(const short8v*)(Ab + arow[2*q + 1] + axor[1]);
      // ---- phase-align, drain LDS, MFMA cluster ----
      __builtin_amdgcn_s_barrier();
      asm volatile("s_waitcnt lgkmcnt(0)" ::: "memory");
      __builtin_amdgcn_sched_barrier(0);
      __builtin_amdgcn_s_setprio(1);
      #pragma unroll
      for (int ni = 0; ni < 4; ni++){
        acc[2*q][ni]   = __builtin_amdgcn_mfma_f32_16x16x32_bf16(a00, bfr0[ni], acc[2*q][ni], 0, 0, 0);
        acc[2*q][ni]   = __builtin_amdgcn_mfma_f32_16x16x32_bf16(a01, bfr1[ni], acc[2*q][ni], 0, 0, 0);
        acc[2*q+1][ni] = __builtin_amdgcn_mfma_f32_16x16x32_bf16(a10, bfr0[ni], acc[2*q+1][ni], 0, 0, 0);
        acc[2*q+1][ni] = __builtin_amdgcn_mfma_f32_16x16x32_bf16(a11, bfr1[ni], acc[2*q+1][ni], 0, 0, 0);
      }
      __builtin_amdgcn_s_setprio(0);
      __builtin_amdgcn_s_barrier();
    }
  }

  // ------------------------- epilogue -------------------------
  if (KIND == 1 && region == 6){
    // shared expert: direct fp32 to d_out
    #pragma unroll
    for (int ni = 0; ni < 4; ni++){
      const int ncol = n0 + wc*64 + ni*16 + fr;
      const float bval = g.bias[ncol];
      #pragma unroll
      for (int mi = 0; mi < 8; mi++){
        const int mrow = m0 + wr*128 + mi*16 + q16*4;
        #pragma unroll
        for (int r = 0; r < 4; r++)
          g.outsh[(size_t)(mrow + r) * 1024 + (ncol & 1023)] = acc[mi][ni][r] + bval;
      }
    }
    return;
  }
  // activated bf16 via swizzled LDS staging, then 512B-coalesced rows
  #pragma unroll
  for (int ni = 0; ni < 4; ni++){
    const int lc = wc*64 + ni*16 + fr;
    const float bval = g.bias[n0 + lc];
    #pragma unroll
    for (int mi = 0; mi < 8; mi++){
      const int lr0 = wr*128 + mi*16 + q16*4;
      #pragma unroll
      for (int r = 0; r < 4; r++){
        float val = acc[mi][ni][r] + bval;
        float o;
        if (KIND == 0){
          if (region < 2 || region == 6)      o = fmaxf(val, 0.f);   // relu
          else if (region < 4)                o = fast_tanh(val);    // bn experts
          else if (region < 6)                o = fast_silu(val);    // ln experts
          else                                o = fast_gelu(val);    // conv experts
        } else {
          o = val;
        }
        const int lr = lr0 + r;
        *(unsigned short*)(sm + lr*512 + ((lc*2) ^ ((lr & 12) << 3))) = f2bf(o);
      }
    }
  }
  __syncthreads();
  #pragma unroll
  for (int it = 0; it < 16; it++){
    const int idx = it*512 + tid;
    const int row = idx >> 5, c16 = idx & 31;
    short8v vv = *(const short8v*)(sm + row*512 + ((c16*16) ^ ((row & 12) << 3)));
    const int m = m0 + row;
    unsigned short* dst;
    if (KIND == 0){
      if (region < 7) dst = g.H + (size_t)m * 7168 + n0 + c16*8;
      else            dst = g.eoc + ((size_t)(region - 7) * NB + m) * 1024 + (n0 & 1023) + c16*8;
    } else {
      dst = g.eolin + ((size_t)region * NB + m) * 1024 + (n0 & 1023) + c16*8;
    }
    *(short8v*)dst = vv;
  }
}

// ---------------------------------------------------------------------------
// 128x128xBK=32 GEMM kept for the gate (KIND 2 only): K=3072 bf16x3 split,
// K-split x2 over blockIdx.z, raw fp32 partials out.
// ---------------------------------------------------------------------------
template<int KIND>
__global__ __launch_bounds__(256, 2) void k_gemm(GemmArgs g){
  __shared__ unsigned short smem[8192];
  unsigned short* sA = smem;
  unsigned short* sB = smem + 4096;

  const int tid  = threadIdx.x;
  const int lane = tid & 63;
  const int wid  = tid >> 6;
  const int m0 = blockIdx.x * 128;
  const int n0 = blockIdx.y * 128;
  const int srow   = tid >> 2;
  const int schunk = (tid & 3) * 8;
  const int K   = g.K;
  const int lda = g.lda;

  unsigned short* lA0 = &sA[wid * 512];
  unsigned short* lA1 = &sA[2048 + wid * 512];
  unsigned short* lB0 = &sB[wid * 512];
  unsigned short* lB1 = &sB[2048 + wid * 512];

  const int wr = wid >> 1, wc = wid & 1;
  const int fr = lane & 15;
  const int kc = (lane >> 4) * 8;

  float4v acc[4][4];
  #pragma unroll
  for (int i = 0; i < 4; i++)
    #pragma unroll
    for (int j = 0; j < 4; j++) acc[i][j] = (float4v){0.f, 0.f, 0.f, 0.f};

  const int kbeg = blockIdx.z * 1536;
  const int kend = kbeg + 1536;

  for (int k0 = kbeg; k0 < kend; k0 += 32){
    int seg = k0 >> 10;
    const unsigned short* Ab = (seg == 1) ? g.A2 : g.A;
    int acol = k0 & 1023;
    gload_lds16(Ab + (size_t)(m0      + srow) * lda + acol + schunk, lA0);
    gload_lds16(Ab + (size_t)(m0 + 64 + srow) * lda + acol + schunk, lA1);
    gload_lds16(g.Bt + (size_t)(n0      + srow) * K + k0 + schunk, lB0);
    gload_lds16(g.Bt + (size_t)(n0 + 64 + srow) * K + k0 + schunk, lB1);
    __syncthreads();
    short8v a[4], b[4];
    #pragma unroll
    for (int mi = 0; mi < 4; mi++) a[mi] = *(const short8v*)&sA[(wr*64 + mi*16 + fr)*32 + kc];
    #pragma unroll
    for (int ni = 0; ni < 4; ni++) b[ni] = *(const short8v*)&sB[(wc*64 + ni*16 + fr)*32 + kc];
    #pragma unroll
    for (int mi = 0; mi < 4; mi++)
      #pragma unroll
      for (int ni = 0; ni < 4; ni++)
        acc[mi][ni] = __builtin_amdgcn_mfma_f32_16x16x32_bf16(a[mi], b[ni], acc[mi][ni], 0, 0, 0);
    __syncthreads();
  }

  const int mr0 = m0 + wr * 64;
  const int nc0 = n0 + wc * 64;
  #pragma unroll
  for (int ni = 0; ni < 4; ni++){
    const int ncol = nc0 + ni * 16 + fr;
    #pragma unroll
    for (int mi = 0; mi < 4; mi++){
      const int mrow = mr0 + mi * 16 + (lane >> 4) * 4;
      float4v v = acc[mi][ni];
      #pragma unroll
      for (int r = 0; r < 4; r++)
        g.T[((size_t)blockIdx.z * NB + mrow + r) * 512 + ncol] = v[r];
    }
  }
}

// ---------------------------------------------------------------------------
// Prep kernels
// ---------------------------------------------------------------------------
__global__ void k_cast_x(const float* __restrict__ x, unsigned short* __restrict__ xb,
                         unsigned short* __restrict__ xlo){
  int i = blockIdx.x * 256 + threadIdx.x;      // 1M threads, 4 elems each
  float4v v = ((const float4v*)x)[i];
  short4v hi, lo;
  #pragma unroll
  for (int j = 0; j < 4; j++){
    unsigned short h = f2bf(v[j]);
    hi[j] = (short)h;
    lo[j] = (short)f2bf(v[j] - bf2f(h));
  }
  ((short4v*)xb)[i]  = hi;
  ((short4v*)xlo)[i] = lo;
}

struct TpArgs { const float* src[14]; unsigned short* dst[14]; };

__global__ void k_transpose(TpArgs a){
  __shared__ float tile[32][33];
  const float* src = a.src[blockIdx.z];
  unsigned short* dst = a.dst[blockIdx.z];
  const int bx = blockIdx.x, by = blockIdx.y;   // bx: n-tile, by: k-tile
  const int tx = threadIdx.x, ty = threadIdx.y;
  #pragma unroll
  for (int i = 0; i < 32; i += 8)
    tile[ty + i][tx] = src[(size_t)(by*32 + ty + i) * 1024 + bx*32 + tx];
  __syncthreads();
  #pragma unroll
  for (int i = 0; i < 32; i += 8)
    dst[(size_t)(bx*32 + ty + i) * 1024 + by*32 + tx] = f2bf(tile[tx][ty + i]);
}

__global__ void k_gateW(const float* __restrict__ gW1, unsigned short* __restrict__ Wg3t){
  __shared__ float tile[32][33];
  const int bx = blockIdx.x, by = blockIdx.y;   // bx: k-tile(32), by: n-tile(16)
  const int tx = threadIdx.x, ty = threadIdx.y;
  #pragma unroll
  for (int i = 0; i < 32; i += 8)
    tile[ty + i][tx] = gW1[(size_t)(bx*32 + ty + i) * 512 + by*32 + tx];
  __syncthreads();
  #pragma unroll
  for (int i = 0; i < 32; i += 8){
    int n = by*32 + ty + i, k = bx*32 + tx;
    float v = tile[tx][ty + i];
    unsigned short hi = f2bf(v);
    unsigned short lo = f2bf(v - bf2f(hi));
    Wg3t[(size_t)n*3072 + k]        = hi;
    Wg3t[(size_t)n*3072 + 1024 + k] = hi;
    Wg3t[(size_t)n*3072 + 2048 + k] = lo;
  }
}

// conv1d+flatten+linear == linear with transformed weight.
__global__ __launch_bounds__(256) void k_convW(const float* __restrict__ convk,
    const float* __restrict__ convW, unsigned short* __restrict__ W1t,
    float* __restrict__ scPart){
  const int e   = blockIdx.z;
  const int ip0 = blockIdx.y * 32;
  const int o   = blockIdx.x * 256 + threadIdx.x;
  const float* W = convW + (size_t)e * 4096 * 1024;
  float kk[4][3];
  #pragma unroll
  for (int c = 0; c < 4; c++)
    #pragma unroll
    for (int j = 0; j < 3; j++) kk[c][j] = convk[e*12 + c*3 + j];

  float wprev[4], wcur[4], sc[4];
  #pragma unroll
  for (int c = 0; c < 4; c++){
    wprev[c] = (ip0 > 0) ? W[(size_t)(c*1024 + ip0 - 1) * 1024 + o] : 0.f;
    wcur[c]  = W[(size_t)(c*1024 + ip0) * 1024 + o];
    sc[c] = 0.f;
  }
  short8v ov[4];
  #pragma unroll
  for (int i = 0; i < 32; i++){
    const int ip = ip0 + i;
    float wnext[4];
    #pragma unroll
    for (int c = 0; c < 4; c++)
      wnext[c] = (ip < 1023) ? W[(size_t)(c*1024 + ip + 1) * 1024 + o] : 0.f;
    float acc = 0.f;
    #pragma unroll
    for (int c = 0; c < 4; c++){
      acc += kk[c][0]*wnext[c] + kk[c][1]*wcur[c] + kk[c][2]*wprev[c];
      sc[c] += wcur[c];
    }
    ov[i >> 3][i & 7] = (short)f2bf(acc);
    #pragma unroll
    for (int c = 0; c < 4; c++){ wprev[c] = wcur[c]; wcur[c] = wnext[c]; }
  }
  unsigned short* drow = W1t + (size_t)(7168 + e*1024 + o) * 1024;
  #pragma unroll
  for (int q = 0; q < 4; q++) *(short8v*)&drow[ip0 + q*8] = ov[q];
  #pragma unroll
  for (int c = 0; c < 4; c++) atomicAdd(&scPart[(e*4 + c)*1024 + o], sc[c]);
}

__global__ void k_conv_bias(const float* __restrict__ convb, const float* __restrict__ convbL,
                            const float* __restrict__ scPart, float* __restrict__ b1cat){
  const int i = blockIdx.x * 256 + threadIdx.x;   // 2048
  const int e = i >> 10, o = i & 1023;
  float b = convbL[i];
  #pragma unroll
  for (int c = 0; c < 4; c++) b += convb[e*4 + c] * scPart[(e*4 + c)*1024 + o];
  b1cat[7168 + i] = b;
}

__global__ void k_biases(const float* mlp_b1, const float* bn_b1, const float* ln_b1, const float* sh_b1,
                         const float* mlp_b2, const float* bn_b2, const float* ln_b2, const float* sh_b2,
                         float* b1cat, float* b2cat){
  int i = blockIdx.x * 256 + threadIdx.x;   // 14336
  if (i < 7168){
    int r = i >> 10;
    float v;
    if (r < 2) v = mlp_b1[i];
    else if (r < 4) v = bn_b1[i - 2048];
    else if (r < 6) v = ln_b1[i - 4096];
    else v = sh_b1[i - 6144];
    b1cat[i] = v;
  } else {
    int j = i - 7168;
    int r = j >> 10;
    float v;
    if (r < 2) v = mlp_b2[j];
    else if (r < 4) v = bn_b2[j - 2048];
    else if (r < 6) v = ln_b2[j - 4096];
    else v = sh_b2[j - 6144];
    b2cat[j] = v;
  }
}

// ---------------------------------------------------------------------------
// Gate finalize
// ---------------------------------------------------------------------------
__global__ __launch_bounds__(256) void k_gate_fin(const float* __restrict__ T,
                                                  const float* __restrict__ gW2,
                                                  const float* __restrict__ gb2,
                                                  const float* __restrict__ gb1,
                                                  const float* __restrict__ w1last,
                                                  const int* __restrict__ mod,
                                                  float* __restrict__ wgt,
                                                  float* __restrict__ usageTok){
  __shared__ float sT[4][512];
  const int tok0 = blockIdx.x * 4;
  #pragma unroll
  for (int i = 0; i < 8; i++){
    int idx = threadIdx.x + i * 256;           // 0..2047
    int tl = idx >> 9, k = idx & 511;
    int tok = tok0 + tl;
    float s = T[(size_t)tok * 512 + k] + T[(size_t)(NB + tok) * 512 + k]
            + gb1[k] + (float)mod[tok] * w1last[k];
    sT[tl][k] = tanhf(s);
  }
  __syncthreads();

  const int tl   = threadIdx.x >> 6;
  const int lane = threadIdx.x & 63;
  const int tok  = tok0 + tl;
  const int e = lane >> 3, sub = lane & 7;
  float p = 0.f;
  for (int k = sub; k < 512; k += 8) p += sT[tl][k] * gW2[k*8 + e];
  p += __shfl_xor(p, 1); p += __shfl_xor(p, 2); p += __shfl_xor(p, 4);
  float le[8];
  #pragma unroll
  for (int q = 0; q < 8; q++) le[q] = __shfl(p, q * 8);
  #pragma unroll
  for (int q = 0; q < 8; q++){
    float l = (le[q] + gb2[q]) / 0.7f;
    le[q] = fminf(fmaxf(l, -10.f), 10.f);
  }
  unsigned sel = 0; int idx4[4]; float bv4[4];
  #pragma unroll
  for (int t4 = 0; t4 < 4; t4++){
    float best = -1e30f; int bi = 0;
    for (int q = 0; q < 8; q++)
      if (!((sel >> q) & 1u) && le[q] > best){ best = le[q]; bi = q; }
    sel |= 1u << bi; idx4[t4] = bi; bv4[t4] = best;
  }
  const float mx = bv4[0];
  float s4 = 0.f, w4[4];
  #pragma unroll
  for (int t4 = 0; t4 < 4; t4++){ w4[t4] = expf(bv4[t4] - mx); s4 += w4[t4]; }
  float su = 0.f, us[8];
  #pragma unroll
  for (int q = 0; q < 8; q++){ us[q] = expf(le[q] - mx); su += us[q]; }
  if (lane == 0){
    float wr[8] = {0,0,0,0,0,0,0,0};
    #pragma unroll
    for (int t4 = 0; t4 < 4; t4++) wr[idx4[t4]] = w4[t4] / s4;
    const float inv = 1.f / su;
    #pragma unroll
    for (int q = 0; q < 8; q++) wgt[(size_t)tok*8 + q] = wr[q];
    #pragma unroll
    for (int q = 0; q < 8; q++) usageTok[(size_t)tok*8 + q] = us[q] * inv;
  }
}

__global__ __launch_bounds__(256) void k_aux(const float* __restrict__ usageTok, float* __restrict__ auxp){
  __shared__ float red[256][8];
  float a[8] = {0,0,0,0,0,0,0,0};
  for (int r = threadIdx.x; r < NB; r += 256){
    float4v v0 = *(const float4v*)&usageTok[(size_t)r * 8];
    float4v v1 = *(const float4v*)&usageTok[(size_t)r * 8 + 4];
    #pragma unroll
    for (int j = 0; j < 4; j++){ a[j] += v0[j]; a[4+j] += v1[j]; }
  }
  #pragma unroll
  for (int q = 0; q < 8; q++) red[threadIdx.x][q] = a[q];
  __syncthreads();
  if (threadIdx.x == 0){
    float s[8] = {0,0,0,0,0,0,0,0};
    for (int t = 0; t < 256; t++)
      #pragma unroll
      for (int q = 0; q < 8; q++) s[q] += red[t][q];
    float acc = 0.f;
    for (int q = 0; q < 8; q++){
      float u = s[q] * (1.f / 4096.f);
      acc += 0.125f * (-2.0794415f - logf(u + 1e-10f));
    }
    auxp[0] = acc * 0.125f;
  }
}

// ---------------------------------------------------------------------------
// BatchNorm (batch stats) over H cols 2048..4095: 2-pass, row-major coalesced.
// ---------------------------------------------------------------------------
__global__ __launch_bounds__(256) void k_bn_stats(const unsigned short* __restrict__ H,
                                                  float* __restrict__ colstats){
  const int r0 = blockIdx.x * 64;
  const int c0 = threadIdx.x * 8;
  float s[8], s2[8];
  #pragma unroll
  for (int j = 0; j < 8; j++){ s[j] = 0.f; s2[j] = 0.f; }
  for (int r = 0; r < 64; r++){
    short8v v = *(const short8v*)&H[(size_t)(r0 + r) * 7168 + 2048 + c0];
    #pragma unroll
    for (int j = 0; j < 8; j++){
      float f = bf2f((unsigned short)v[j]);
      s[j] += f; s2[j] += f * f;
    }
  }
  #pragma unroll
  for (int j = 0; j < 8; j++){
    atomicAdd(&colstats[c0 + j], s[j]);
    atomicAdd(&colstats[2048 + c0 + j], s2[j]);
  }
}

__global__ __launch_bounds__(256) void k_bn_apply(unsigned short* __restrict__ H,
    const float* __restrict__ colstats,
    const float* __restrict__ bn_g, const float* __restrict__ bn_be){
  const int r0 = blockIdx.x * 16;
  const int c0 = threadIdx.x * 8;
  float mul[8], add[8];
  #pragma unroll
  for (int j = 0; j < 8; j++){
    const int c = c0 + j;
    float m   = colstats[c] * (1.f / NB);
    float var = colstats[2048 + c] * (1.f / NB) - m * m;
    float inv = 1.f / sqrtf(var + 1e-5f);
    const int e = c >> 10, cc = c & 1023;
    float g = bn_g[e*1024 + cc], b = bn_be[e*1024 + cc];
    mul[j] = g * inv;
    add[j] = b - m * g * inv;
  }
  for (int r = 0; r < 16; r++){
    unsigned short* p = &H[(size_t)(r0 + r) * 7168 + 2048 + c0];
    short8v v = *(const short8v*)p;
    short8v o;
    #pragma unroll
    for (int j = 0; j < 8; j++)
      o[j] = (short)f2bf(bf2f((unsigned short)v[j]) * mul[j] + add[j]);
    *(short8v*)p = o;
  }
}

// ---------------------------------------------------------------------------
// Row LayerNorm for ln0/ln1/shared slices of H, in place
// ---------------------------------------------------------------------------
__global__ __launch_bounds__(128) void k_ln(unsigned short* __restrict__ H,
    const float* __restrict__ ln_g, const float* __restrict__ ln_be,
    const float* __restrict__ sh_g, const float* __restrict__ sh_be){
  const int row = blockIdx.x, sl = blockIdx.y;
  unsigned short* p = H + (size_t)row * 7168 + 4096 + sl * 1024;
  const int t = threadIdx.x, lane = t & 63, w = t >> 6;
  short8v raw = *(const short8v*)&p[t * 8];
  float v[8]; float s = 0.f, s2 = 0.f;
  #pragma unroll
  for (int j = 0; j < 8; j++){ v[j] = bf2f((unsigned short)raw[j]); s += v[j]; s2 += v[j]*v[j]; }
  #pragma unroll
  for (int d = 1; d < 64; d <<= 1){ s += __shfl_xor(s, d); s2 += __shfl_xor(s2, d); }
  __shared__ float red[4];
  if (lane == 0){ red[w*2] = s; red[w*2+1] = s2; }
  __syncthreads();
  float ts = red[0] + red[2], tq = red[1] + red[3];
  float m   = ts * (1.f / 1024.f);
  float var = tq * (1.f / 1024.f) - m*m;
  float inv = 1.f / sqrtf(var + 1e-5f);
  const float* gp = (sl == 0) ? ln_g : (sl == 1) ? ln_g + 1024 : sh_g;
  const float* bp = (sl == 0) ? ln_be : (sl == 1) ? ln_be + 1024 : sh_be;
  short8v outv;
  #pragma unroll
  for (int j = 0; j < 8; j++){
    int cc = t*8 + j;
    outv[j] = (short)f2bf((v[j] - m) * inv * gp[cc] + bp[cc]);
  }
  *(short8v*)&p[t * 8] = outv;
}

// ---------------------------------------------------------------------------
// private = sum_e wgt[b][e] * expert_out[e][b,:]
// ---------------------------------------------------------------------------
__global__ __launch_bounds__(256) void k_combine(const unsigned short* __restrict__ eolin,
    const unsigned short* __restrict__ eoc, const float* __restrict__ wgt, float* __restrict__ priv){
  const int i = blockIdx.x * 256 + threadIdx.x;  // 524288
  const int b = i >> 7;
  const int c = (i & 127) * 8;
  const float* w = wgt + (size_t)b * 8;
  float acc[8];
  #pragma unroll
  for (int j = 0; j < 8; j++) acc[j] = 0.f;
  const int emap[6] = {0, 1, 2, 3, 6, 7};
  #pragma unroll
  for (int r = 0; r < 6; r++){
    float we = w[emap[r]];
    short8v v = *(const short8v*)&eolin[((size_t)r * NB + b) * 1024 + c];
    #pragma unroll
    for (int j = 0; j < 8; j++) acc[j] += we * bf2f((unsigned short)v[j]);
  }
  #pragma unroll
  for (int e2 = 0; e2 < 2; e2++){
    float we = w[4 + e2];
    short8v v = *(const short8v*)&eoc[((size_t)e2 * NB + b) * 1024 + c];
    #pragma unroll
    for (int j = 0; j < 8; j++) acc[j] += we * bf2f((unsigned short)v[j]);
  }
  float4v o0 = {acc[0], acc[1], acc[2], acc[3]};
  float4v o1 = {acc[4], acc[5], acc[6], acc[7]};
  float4v* dst = (float4v*)&priv[(size_t)b * 1024 + c];
  dst[0] = o0; dst[1] = o1;
}

// ---------------------------------------------------------------------------
// Host launch
// ---------------------------------------------------------------------------
extern "C" void kernel_launch(void* const* d_in, const int* in_sizes, int n_in,
                              void* d_out, int out_size, void* d_ws, size_t ws_size,
                              hipStream_t stream){
  const float* x      = (const float*)d_in[0];
  const int*   modal  = (const int*)d_in[1];
  const float* mlp_W1 = (const float*)d_in[2];
  const float* mlp_b1 = (const float*)d_in[3];
  const float* mlp_W2 = (const float*)d_in[4];
  const float* mlp_b2 = (const float*)d_in[5];
  const float* bn_W1  = (const float*)d_in[6];
  const float* bn_b1  = (const float*)d_in[7];
  const float* bn_g   = (const float*)d_in[8];
  const float* bn_be  = (const float*)d_in[9];
  const float* bn_W2  = (const float*)d_in[10];
  const float* bn_b2  = (const float*)d_in[11];
  const float* conv_k = (const float*)d_in[12];
  const float* conv_b = (const float*)d_in[13];
  const float* conv_W = (const float*)d_in[14];
  const float* conv_bL= (const float*)d_in[15];
  const float* ln_W1  = (const float*)d_in[16];
  const float* ln_b1  = (const float*)d_in[17];
  const float* ln_g   = (const float*)d_in[18];
  const float* ln_be  = (const float*)d_in[19];
  const float* ln_W2  = (const float*)d_in[20];
  const float* ln_b2  = (const float*)d_in[21];
  const float* sh_W1  = (const float*)d_in[22];
  const float* sh_b1  = (const float*)d_in[23];
  const float* sh_g   = (const float*)d_in[24];
  const float* sh_be  = (const float*)d_in[25];
  const float* sh_W2  = (const float*)d_in[26];
  const float* sh_b2  = (const float*)d_in[27];
  const float* g_W1   = (const float*)d_in[28];
  const float* g_b1   = (const float*)d_in[29];
  const float* g_W2   = (const float*)d_in[30];
  const float* g_b2   = (const float*)d_in[31];

  char* ws = (char*)d_ws;
  size_t o_xb   = 0;
  size_t o_xlo  = o_xb  + 8388608ull;
  size_t o_W1t  = o_xlo + 8388608ull;    // [9216][1024] bf16
  size_t o_W2t  = o_W1t + 18874368ull;   // [7168][1024] bf16
  size_t o_Wg   = o_W2t + 14680064ull;   // [512][3072] bf16
  size_t o_H    = o_Wg  + 3145728ull;    // [4096][7168] bf16 (T aliases first 16MB)
  size_t o_eoc  = o_H   + 58720256ull;   // [2][4096][1024] bf16
  size_t o_eol  = o_eoc + 16777216ull;   // [6][4096][1024] bf16
  size_t o_b1   = o_eol + 50331648ull;   // [9216] f32
  size_t o_b2   = o_b1  + 36864ull;      // [7168] f32
  size_t o_wgt  = o_b2  + 28672ull;      // [4096][8] f32
  size_t o_ut   = o_wgt + 131072ull;     // [4096][8] f32 usage probs
  size_t o_scp  = o_ut  + 131072ull;     // [2][4][1024] f32 conv colsum partials
  size_t o_cst  = o_scp + 32768ull;      // [2][2048] f32 bn colstats

  unsigned short* xb    = (unsigned short*)(ws + o_xb);
  unsigned short* xlo   = (unsigned short*)(ws + o_xlo);
  unsigned short* W1t   = (unsigned short*)(ws + o_W1t);
  unsigned short* W2t   = (unsigned short*)(ws + o_W2t);
  unsigned short* Wg3t  = (unsigned short*)(ws + o_Wg);
  unsigned short* H     = (unsigned short*)(ws + o_H);
  float*          T     = (float*)(ws + o_H);   // dead before H is written
  unsigned short* eoc   = (unsigned short*)(ws + o_eoc);
  unsigned short* eolin = (unsigned short*)(ws + o_eol);
  float*          b1cat = (float*)(ws + o_b1);
  float*          b2cat = (float*)(ws + o_b2);
  float*          wgt   = (float*)(ws + o_wgt);
  float*          usageTok = (float*)(ws + o_ut);
  float*          scPart   = (float*)(ws + o_scp);
  float*          colstats = (float*)(ws + o_cst);

  float* outF   = (float*)d_out;
  float* shared = outF;                       // [4096][1024]
  float* priv   = outF + (size_t)NB * 1024;   // [4096][1024]
  float* auxp   = outF + (size_t)2 * NB * 1024; // [1]

  hipMemsetAsync(scPart, 0, 32768, stream);
  hipMemsetAsync(colstats, 0, 16384, stream);

  k_cast_x<<<4096, 256, 0, stream>>>(x, xb, xlo);

  TpArgs tp;
  for (int e = 0; e < 2; e++){
    tp.src[0 + e] = mlp_W1 + (size_t)e * 1048576;
    tp.src[2 + e] = bn_W1  + (size_t)e * 1048576;
    tp.src[4 + e] = ln_W1  + (size_t)e * 1048576;
  }
  tp.src[6] = sh_W1;
  for (int e = 0; e < 2; e++){
    tp.src[7 + e]  = mlp_W2 + (size_t)e * 1048576;
    tp.src[9 + e]  = bn_W2  + (size_t)e * 1048576;
    tp.src[11 + e] = ln_W2  + (size_t)e * 1048576;
  }
  tp.src[13] = sh_W2;
  for (int s = 0; s < 7; s++)  tp.dst[s] = W1t + (size_t)s * 1048576;
  for (int s = 7; s < 14; s++) tp.dst[s] = W2t + (size_t)(s - 7) * 1048576;
  k_transpose<<<dim3(32, 32, 14), dim3(32, 8), 0, stream>>>(tp);

  k_gateW<<<dim3(32, 16), dim3(32, 8), 0, stream>>>(g_W1, Wg3t);
  k_convW<<<dim3(4, 32, 2), 256, 0, stream>>>(conv_k, conv_W, W1t, scPart);
  k_conv_bias<<<8, 256, 0, stream>>>(conv_b, conv_bL, scPart, b1cat);
  k_biases<<<56, 256, 0, stream>>>(mlp_b1, bn_b1, ln_b1, sh_b1, mlp_b2, bn_b2, ln_b2, sh_b2, b1cat, b2cat);

  // ---- gate (K-split x2) ----
  GemmArgs ga = {};
  ga.A = xb; ga.A2 = xlo; ga.Bt = Wg3t; ga.lda = 1024; ga.K = 3072;
  ga.T = T;
  k_gemm<2><<<dim3(32, 4, 2), 256, 0, stream>>>(ga);
  k_gate_fin<<<1024, 256, 0, stream>>>(T, g_W2, g_b2, g_b1, g_W1 + (size_t)1024 * 512,
                                       modal, wgt, usageTok);
  k_aux<<<1, 256, 0, stream>>>(usageTok, auxp);

  // ---- fused layer 1: 256^2 fine-phased GEMM (36 N-tiles x 16 M-tiles) ----
  GemmArgs g1 = {};
  g1.A = xb; g1.Bt = W1t; g1.lda = 1024; g1.K = 1024;
  g1.bias = b1cat; g1.H = H; g1.eoc = eoc;
  k_gemm8<0><<<dim3(576), 512, 0, stream>>>(g1);

  k_bn_stats<<<64, 256, 0, stream>>>(H, colstats);
  k_bn_apply<<<256, 256, 0, stream>>>(H, colstats, bn_g, bn_be);
  k_ln<<<dim3(4096, 3), 128, 0, stream>>>(H, ln_g, ln_be, sh_g, sh_be);

  // ---- fused layer 2: 256^2 (28 N-tiles x 16 M-tiles) ----
  GemmArgs g2 = {};
  g2.A = H; g2.Bt = W2t; g2.lda = 7168; g2.K = 1024;
  g2.bias = b2cat; g2.eolin = eolin; g2.outsh = shared;
  k_gemm8<1><<<dim3(448), 512, 0, stream>>>(g2);

  k_combine<<<2048, 256, 0, stream>>>(eolin, eoc, wgt, priv);
}

// Round 8
// 503.519 us; speedup vs baseline: 1.1897x; 1.1897x over previous
//
#include <hip/hip_runtime.h>
#include <cstdint>
#include <cstddef>

// ---------------------------------------------------------------------------
// Problem constants (B=4096, DIN=DOUT=1024, E=8, K=4)
// ---------------------------------------------------------------------------
#define NB 4096
#define ND 1024

typedef __attribute__((ext_vector_type(8))) short short8v;
typedef __attribute__((ext_vector_type(4))) short short4v;
typedef __attribute__((ext_vector_type(4))) float float4v;

__device__ __forceinline__ unsigned short f2bf(float x){
  union{float f; unsigned u;} v; v.f = x;
  unsigned r = v.u + 0x7FFFu + ((v.u >> 16) & 1u);  // RNE
  return (unsigned short)(r >> 16);
}
__device__ __forceinline__ float bf2f(unsigned short h){
  union{unsigned u; float f;} v; v.u = ((unsigned)h) << 16; return v.f;
}

// fast activations (err ~1e-7, well under bf16 eps)
__device__ __forceinline__ float fast_tanh(float x){
  float xc = fminf(fmaxf(x, -15.f), 15.f);
  float e2 = __expf(2.f * xc);
  return 1.f - 2.f / (e2 + 1.f);
}
__device__ __forceinline__ float fast_silu(float x){
  return x / (1.f + __expf(-x));
}
__device__ __forceinline__ float fast_gelu(float x){
  // exact gelu with Abramowitz-Stegun 7.1.26 erf (|err| <= 1.5e-7)
  float a = fabsf(x) * 0.70710678118654752f;
  float t = 1.f / (1.f + 0.3275911f * a);
  float poly = t * (0.254829592f + t * (-0.284496736f + t * (1.421413741f +
               t * (-1.453152027f + t * 1.061405429f))));
  float erf = 1.f - poly * __expf(-a * a);
  erf = (x < 0.f) ? -erf : erf;
  return 0.5f * x * (1.f + erf);
}

typedef const __attribute__((address_space(1))) unsigned int* gas_ptr;
typedef __attribute__((address_space(3))) unsigned int* las_ptr;

__device__ __forceinline__ void gload_lds16(const void* g, void* l){
  __builtin_amdgcn_global_load_lds((gas_ptr)g, (las_ptr)l, 16, 0, 0);
}

struct GemmArgs {
  const unsigned short* A;     // bf16 [M][lda]
  const unsigned short* A2;    // xlo (gate segments)
  const unsigned short* Bt;    // bf16 [N][K] main weights
  const unsigned short* Bt2;   // gate Wg3t [512][3072]
  int lda;
  int K;                       // main K (1024)
  const float* bias;           // [N]
  unsigned short* H;           // KIND0 dest (cols 0..7167)
  unsigned short* eoc;         // KIND0 conv dest [2][4096][1024]
  unsigned short* eolin;       // KIND1 dest [6][4096][1024]
  float* outsh;                // KIND1 shared dest (d_out)
  float* T;                    // gate raw fp32 [4096][512]
};

// ---------------------------------------------------------------------------
// 128x128xBK=64 bf16 MFMA GEMM, single-buffered (proven round-3 structure,
// upgraded: BK=64 halves barriers; both-sides XOR chunk-swizzle kills the
// ds_read bank conflicts; XCD-bijective block swizzle).
// KIND 0: fused layer-1 (N=9216) + gate GEMM1 (first 128 blocks, K=3072
//         bf16x3, raw fp32 -> T). KIND 1: fused layer-2 (N=7168).
// LDS tile layout per operand: [128 rows][8 chunks of 16B], chunk swizzled
// by (row&7): stored chunk c holds global chunk c^(row&7). Staging keeps the
// LDS dest linear (gload_lds requirement) and inverse-swizzles the global
// source column; ds_reads apply the same XOR.
// ---------------------------------------------------------------------------
template<int KIND>
__global__ __launch_bounds__(256, 3) void k_gemm128(GemmArgs g){
  __shared__ __align__(16) char sm[32768];
  char* sA = sm;
  char* sB = sm + 16384;
  const int tid  = threadIdx.x;
  const int lane = tid & 63;
  const int wid  = tid >> 6;
  const int wr = wid >> 1, wc = wid & 1;
  const int fr = lane & 15;
  const int q16 = lane >> 4;            // 0..3
  const int srw  = tid >> 3;            // 0..31 row within sweep
  const int scol = (((tid & 7) ^ (srw & 7)) << 3);  // inverse-swizzled col (elems)

  int m0, n0; bool gateblk = false;
  if (KIND == 0){
    const int idx = blockIdx.x;
    if (idx < 128){            // gate tiles first (3x K, start early)
      gateblk = true; m0 = (idx >> 2) * 128; n0 = (idx & 3) * 128;
    } else {
      const int w = idx - 128;
      const int wp = (w & 7) * 288 + (w >> 3);   // 2304/8, bijective
      m0 = (wp & 31) * 128; n0 = (wp >> 5) * 128;
    }
  } else {
    const int wp = ((int)blockIdx.x & 7) * 224 + ((int)blockIdx.x >> 3); // 1792/8
    m0 = (wp & 31) * 128; n0 = (wp >> 5) * 128;
  }
  const int region = n0 >> 10;
  const unsigned short* A0 = (KIND == 1) ? g.A + (size_t)region * 1024 : g.A;
  const int lda = g.lda;
  const unsigned short* Bg = gateblk ? g.Bt2 : g.Bt;
  const int ldb = gateblk ? 3072 : g.K;
  const int KK  = gateblk ? 3072 : g.K;

  float4v acc[4][4];
  #pragma unroll
  for (int i = 0; i < 4; i++)
    #pragma unroll
    for (int j = 0; j < 4; j++) acc[i][j] = (float4v){0.f, 0.f, 0.f, 0.f};

  for (int k0 = 0; k0 < KK; k0 += 64){
    const unsigned short* Ag = A0;
    int acol = k0;
    if (KIND == 0 && gateblk){
      const int seg = k0 >> 10;                 // 0:xhi 1:xlo 2:xhi
      Ag = (seg == 1) ? g.A2 : g.A;
      acol = k0 & 1023;
    }
    #pragma unroll
    for (int s = 0; s < 4; s++)
      gload_lds16(Ag + (size_t)(m0 + s*32 + srw) * lda + acol + scol, sA + s*4096 + tid*16);
    #pragma unroll
    for (int s = 0; s < 4; s++)
      gload_lds16(Bg + (size_t)(n0 + s*32 + srw) * ldb + k0 + scol, sB + s*4096 + tid*16);
    __syncthreads();
    #pragma unroll
    for (int ks = 0; ks < 2; ks++){
      const int kb = ks*64 + q16*16;
      short8v a[4], b[4];
      #pragma unroll
      for (int mi = 0; mi < 4; mi++){
        const int row = wr*64 + mi*16 + fr;
        a[mi] = *(const short8v*)(sA + row*128 + (kb ^ ((row & 7) << 4)));
      }
      #pragma unroll
      for (int ni = 0; ni < 4; ni++){
        const int row = wc*64 + ni*16 + fr;
        b[ni] = *(const short8v*)(sB + row*128 + (kb ^ ((row & 7) << 4)));
      }
      #pragma unroll
      for (int mi = 0; mi < 4; mi++)
        #pragma unroll
        for (int ni = 0; ni < 4; ni++)
          acc[mi][ni] = __builtin_amdgcn_mfma_f32_16x16x32_bf16(a[mi], b[ni], acc[mi][ni], 0, 0, 0);
    }
    __syncthreads();
  }

  // ------------------------- epilogues -------------------------
  if (KIND == 0 && gateblk){
    // raw fp32 partial logits-pre-tanh (bias/mod/tanh in k_gate_fin)
    #pragma unroll
    for (int ni = 0; ni < 4; ni++){
      const int ncol = n0 + wc*64 + ni*16 + fr;
      #pragma unroll
      for (int mi = 0; mi < 4; mi++){
        const int mrow = m0 + wr*64 + mi*16 + q16*4;
        #pragma unroll
        for (int r = 0; r < 4; r++)
          g.T[(size_t)(mrow + r) * 512 + ncol] = acc[mi][ni][r];
      }
    }
    return;
  }
  if (KIND == 1 && region == 6){
    // shared expert: direct fp32 to d_out
    #pragma unroll
    for (int ni = 0; ni < 4; ni++){
      const int ncol = n0 + wc*64 + ni*16 + fr;
      const float bval = g.bias[ncol];
      #pragma unroll
      for (int mi = 0; mi < 4; mi++){
        const int mrow = m0 + wr*64 + mi*16 + q16*4;
        #pragma unroll
        for (int r = 0; r < 4; r++)
          g.outsh[(size_t)(mrow + r) * 1024 + (ncol & 1023)] = acc[mi][ni][r] + bval;
      }
    }
    return;
  }
  // activated bf16 via swizzled LDS staging, then 256B-coalesced row writes
  __syncthreads();
  #pragma unroll
  for (int ni = 0; ni < 4; ni++){
    const int lc = wc*64 + ni*16 + fr;
    const float bval = g.bias[n0 + lc];
    #pragma unroll
    for (int mi = 0; mi < 4; mi++){
      const int lr0 = wr*64 + mi*16 + q16*4;
      #pragma unroll
      for (int r = 0; r < 4; r++){
        float val = acc[mi][ni][r] + bval;
        float o;
        if (KIND == 0){
          if (region < 2 || region == 6)      o = fmaxf(val, 0.f);   // relu
          else if (region < 4)                o = fast_tanh(val);    // bn experts
          else if (region < 6)                o = fast_silu(val);    // ln experts
          else                                o = fast_gelu(val);    // conv experts
        } else {
          o = val;
        }
        const int lr = lr0 + r;
        *(unsigned short*)(sm + lr*256 + ((lc*2) ^ ((lr & 7) << 4))) = f2bf(o);
      }
    }
  }
  __syncthreads();
  const int ct = tid & 15;
  const int rb = tid >> 4;
  #pragma unroll
  for (int p = 0; p < 8; p++){
    const int lr = rb + p*16;
    short8v vv = *(const short8v*)(sm + lr*256 + ((ct*16) ^ ((lr & 7) << 4)));
    const int m = m0 + lr;
    unsigned short* dst;
    if (KIND == 0){
      if (region < 7) dst = g.H + (size_t)m * 7168 + n0 + ct*8;
      else            dst = g.eoc + ((size_t)(region - 7) * NB + m) * 1024 + (n0 & 1023) + ct*8;
    } else {
      dst = g.eolin + ((size_t)region * NB + m) * 1024 + (n0 & 1023) + ct*8;
    }
    *(short8v*)dst = vv;
  }
}

// ---------------------------------------------------------------------------
// Prep kernels
// ---------------------------------------------------------------------------
__global__ void k_cast_x(const float* __restrict__ x, unsigned short* __restrict__ xb,
                         unsigned short* __restrict__ xlo){
  int i = blockIdx.x * 256 + threadIdx.x;      // 1M threads, 4 elems each
  float4v v = ((const float4v*)x)[i];
  short4v hi, lo;
  #pragma unroll
  for (int j = 0; j < 4; j++){
    unsigned short h = f2bf(v[j]);
    hi[j] = (short)h;
    lo[j] = (short)f2bf(v[j] - bf2f(h));
  }
  ((short4v*)xb)[i]  = hi;
  ((short4v*)xlo)[i] = lo;
}

struct TpArgs { const float* src[14]; unsigned short* dst[14]; };

__global__ void k_transpose(TpArgs a){
  __shared__ float tile[32][33];
  const float* src = a.src[blockIdx.z];
  unsigned short* dst = a.dst[blockIdx.z];
  const int bx = blockIdx.x, by = blockIdx.y;   // bx: n-tile, by: k-tile
  const int tx = threadIdx.x, ty = threadIdx.y;
  #pragma unroll
  for (int i = 0; i < 32; i += 8)
    tile[ty + i][tx] = src[(size_t)(by*32 + ty + i) * 1024 + bx*32 + tx];
  __syncthreads();
  #pragma unroll
  for (int i = 0; i < 32; i += 8)
    dst[(size_t)(bx*32 + ty + i) * 1024 + by*32 + tx] = f2bf(tile[tx][ty + i]);
}

__global__ void k_gateW(const float* __restrict__ gW1, unsigned short* __restrict__ Wg3t){
  __shared__ float tile[32][33];
  const int bx = blockIdx.x, by = blockIdx.y;   // bx: k-tile(32), by: n-tile(16)
  const int tx = threadIdx.x, ty = threadIdx.y;
  #pragma unroll
  for (int i = 0; i < 32; i += 8)
    tile[ty + i][tx] = gW1[(size_t)(bx*32 + ty + i) * 512 + by*32 + tx];
  __syncthreads();
  #pragma unroll
  for (int i = 0; i < 32; i += 8){
    int n = by*32 + ty + i, k = bx*32 + tx;
    float v = tile[tx][ty + i];
    unsigned short hi = f2bf(v);
    unsigned short lo = f2bf(v - bf2f(hi));
    Wg3t[(size_t)n*3072 + k]        = hi;
    Wg3t[(size_t)n*3072 + 1024 + k] = hi;
    Wg3t[(size_t)n*3072 + 2048 + k] = lo;
  }
}

// conv1d+flatten+linear == linear with transformed weight.
__global__ __launch_bounds__(256) void k_convW(const float* __restrict__ convk,
    const float* __restrict__ convW, unsigned short* __restrict__ W1t,
    float* __restrict__ scPart){
  const int e   = blockIdx.z;
  const int ip0 = blockIdx.y * 32;
  const int o   = blockIdx.x * 256 + threadIdx.x;
  const float* W = convW + (size_t)e * 4096 * 1024;
  float kk[4][3];
  #pragma unroll
  for (int c = 0; c < 4; c++)
    #pragma unroll
    for (int j = 0; j < 3; j++) kk[c][j] = convk[e*12 + c*3 + j];

  float wprev[4], wcur[4], sc[4];
  #pragma unroll
  for (int c = 0; c < 4; c++){
    wprev[c] = (ip0 > 0) ? W[(size_t)(c*1024 + ip0 - 1) * 1024 + o] : 0.f;
    wcur[c]  = W[(size_t)(c*1024 + ip0) * 1024 + o];
    sc[c] = 0.f;
  }
  short8v ov[4];
  #pragma unroll
  for (int i = 0; i < 32; i++){
    const int ip = ip0 + i;
    float wnext[4];
    #pragma unroll
    for (int c = 0; c < 4; c++)
      wnext[c] = (ip < 1023) ? W[(size_t)(c*1024 + ip + 1) * 1024 + o] : 0.f;
    float acc = 0.f;
    #pragma unroll
    for (int c = 0; c < 4; c++){
      acc += kk[c][0]*wnext[c] + kk[c][1]*wcur[c] + kk[c][2]*wprev[c];
      sc[c] += wcur[c];
    }
    ov[i >> 3][i & 7] = (short)f2bf(acc);
    #pragma unroll
    for (int c = 0; c < 4; c++){ wprev[c] = wcur[c]; wcur[c] = wnext[c]; }
  }
  unsigned short* drow = W1t + (size_t)(7168 + e*1024 + o) * 1024;
  #pragma unroll
  for (int q = 0; q < 4; q++) *(short8v*)&drow[ip0 + q*8] = ov[q];
  #pragma unroll
  for (int c = 0; c < 4; c++) atomicAdd(&scPart[(e*4 + c)*1024 + o], sc[c]);
}

// All bias concatenation (incl. conv folded bias) in one kernel. 16384 thr.
__global__ void k_biases(const float* mlp_b1, const float* bn_b1, const float* ln_b1, const float* sh_b1,
                         const float* mlp_b2, const float* bn_b2, const float* ln_b2, const float* sh_b2,
                         const float* convb, const float* convbL, const float* scPart,
                         float* b1cat, float* b2cat){
  int i = blockIdx.x * 256 + threadIdx.x;   // 16384
  if (i < 7168){
    int r = i >> 10;
    float v;
    if (r < 2) v = mlp_b1[i];
    else if (r < 4) v = bn_b1[i - 2048];
    else if (r < 6) v = ln_b1[i - 4096];
    else v = sh_b1[i - 6144];
    b1cat[i] = v;
  } else if (i < 9216){
    int j = i - 7168;                       // conv region
    int e = j >> 10, o = j & 1023;
    float b = convbL[j];
    #pragma unroll
    for (int c = 0; c < 4; c++) b += convb[e*4 + c] * scPart[(e*4 + c)*1024 + o];
    b1cat[i] = b;
  } else {
    int j = i - 9216;
    int r = j >> 10;
    float v;
    if (r < 2) v = mlp_b2[j];
    else if (r < 4) v = bn_b2[j - 2048];
    else if (r < 6) v = ln_b2[j - 4096];
    else v = sh_b2[j - 6144];
    b2cat[j] = v;
  }
}

// ---------------------------------------------------------------------------
// Gate finalize: T + bias + modality -> tanh (once per col via LDS), fp32
// GEMM2 (512x8), clip, top-4, softmax weights, per-token usage probs.
// ---------------------------------------------------------------------------
__global__ __launch_bounds__(256) void k_gate_fin(const float* __restrict__ T,
                                                  const float* __restrict__ gW2,
                                                  const float* __restrict__ gb2,
                                                  const float* __restrict__ gb1,
                                                  const float* __restrict__ w1last,
                                                  const int* __restrict__ mod,
                                                  float* __restrict__ wgt,
                                                  float* __restrict__ usageTok){
  __shared__ float sT[4][512];
  const int tok0 = blockIdx.x * 4;
  #pragma unroll
  for (int i = 0; i < 8; i++){
    int idx = threadIdx.x + i * 256;           // 0..2047
    int tl = idx >> 9, k = idx & 511;
    int tok = tok0 + tl;
    float s = T[(size_t)tok * 512 + k] + gb1[k] + (float)mod[tok] * w1last[k];
    sT[tl][k] = tanhf(s);
  }
  __syncthreads();

  const int tl   = threadIdx.x >> 6;
  const int lane = threadIdx.x & 63;
  const int tok  = tok0 + tl;
  const int e = lane >> 3, sub = lane & 7;
  float p = 0.f;
  for (int k = sub; k < 512; k += 8) p += sT[tl][k] * gW2[k*8 + e];
  p += __shfl_xor(p, 1); p += __shfl_xor(p, 2); p += __shfl_xor(p, 4);
  float le[8];
  #pragma unroll
  for (int q = 0; q < 8; q++) le[q] = __shfl(p, q * 8);
  #pragma unroll
  for (int q = 0; q < 8; q++){
    float l = (le[q] + gb2[q]) / 0.7f;
    le[q] = fminf(fmaxf(l, -10.f), 10.f);
  }
  unsigned sel = 0; int idx4[4]; float bv4[4];
  #pragma unroll
  for (int t4 = 0; t4 < 4; t4++){
    float best = -1e30f; int bi = 0;
    for (int q = 0; q < 8; q++)
      if (!((sel >> q) & 1u) && le[q] > best){ best = le[q]; bi = q; }
    sel |= 1u << bi; idx4[t4] = bi; bv4[t4] = best;
  }
  const float mx = bv4[0];
  float s4 = 0.f, w4[4];
  #pragma unroll
  for (int t4 = 0; t4 < 4; t4++){ w4[t4] = expf(bv4[t4] - mx); s4 += w4[t4]; }
  float su = 0.f, us[8];
  #pragma unroll
  for (int q = 0; q < 8; q++){ us[q] = expf(le[q] - mx); su += us[q]; }
  if (lane == 0){
    float wr[8] = {0,0,0,0,0,0,0,0};
    #pragma unroll
    for (int t4 = 0; t4 < 4; t4++) wr[idx4[t4]] = w4[t4] / s4;
    const float inv = 1.f / su;
    #pragma unroll
    for (int q = 0; q < 8; q++) wgt[(size_t)tok*8 + q] = wr[q];
    #pragma unroll
    for (int q = 0; q < 8; q++) usageTok[(size_t)tok*8 + q] = us[q] * inv;
  }
}

__global__ __launch_bounds__(256) void k_aux(const float* __restrict__ usageTok, float* __restrict__ auxp){
  __shared__ float red[256][8];
  float a[8] = {0,0,0,0,0,0,0,0};
  for (int r = threadIdx.x; r < NB; r += 256){
    float4v v0 = *(const float4v*)&usageTok[(size_t)r * 8];
    float4v v1 = *(const float4v*)&usageTok[(size_t)r * 8 + 4];
    #pragma unroll
    for (int j = 0; j < 4; j++){ a[j] += v0[j]; a[4+j] += v1[j]; }
  }
  #pragma unroll
  for (int q = 0; q < 8; q++) red[threadIdx.x][q] = a[q];
  __syncthreads();
  if (threadIdx.x == 0){
    float s[8] = {0,0,0,0,0,0,0,0};
    for (int t = 0; t < 256; t++)
      #pragma unroll
      for (int q = 0; q < 8; q++) s[q] += red[t][q];
    float acc = 0.f;
    for (int q = 0; q < 8; q++){
      float u = s[q] * (1.f / 4096.f);
      acc += 0.125f * (-2.0794415f - logf(u + 1e-10f));
    }
    auxp[0] = acc * 0.125f;
  }
}

// ---------------------------------------------------------------------------
// BatchNorm (batch stats) over H cols 2048..4095: 2-pass, row-major coalesced.
// ---------------------------------------------------------------------------
__global__ __launch_bounds__(256) void k_bn_stats(const unsigned short* __restrict__ H,
                                                  float* __restrict__ colstats){
  const int r0 = blockIdx.x * 64;
  const int c0 = threadIdx.x * 8;
  float s[8], s2[8];
  #pragma unroll
  for (int j = 0; j < 8; j++){ s[j] = 0.f; s2[j] = 0.f; }
  for (int r = 0; r < 64; r++){
    short8v v = *(const short8v*)&H[(size_t)(r0 + r) * 7168 + 2048 + c0];
    #pragma unroll
    for (int j = 0; j < 8; j++){
      float f = bf2f((unsigned short)v[j]);
      s[j] += f; s2[j] += f * f;
    }
  }
  #pragma unroll
  for (int j = 0; j < 8; j++){
    atomicAdd(&colstats[c0 + j], s[j]);
    atomicAdd(&colstats[2048 + c0 + j], s2[j]);
  }
}

__global__ __launch_bounds__(256) void k_bn_apply(unsigned short* __restrict__ H,
    const float* __restrict__ colstats,
    const float* __restrict__ bn_g, const float* __restrict__ bn_be){
  const int r0 = blockIdx.x * 16;
  const int c0 = threadIdx.x * 8;
  float mul[8], add[8];
  #pragma unroll
  for (int j = 0; j < 8; j++){
    const int c = c0 + j;
    float m   = colstats[c] * (1.f / NB);
    float var = colstats[2048 + c] * (1.f / NB) - m * m;
    float inv = 1.f / sqrtf(var + 1e-5f);
    const int e = c >> 10, cc = c & 1023;
    float g = bn_g[e*1024 + cc], b = bn_be[e*1024 + cc];
    mul[j] = g * inv;
    add[j] = b - m * g * inv;
  }
  for (int r = 0; r < 16; r++){
    unsigned short* p = &H[(size_t)(r0 + r) * 7168 + 2048 + c0];
    short8v v = *(const short8v*)p;
    short8v o;
    #pragma unroll
    for (int j = 0; j < 8; j++)
      o[j] = (short)f2bf(bf2f((unsigned short)v[j]) * mul[j] + add[j]);
    *(short8v*)p = o;
  }
}

// ---------------------------------------------------------------------------
// Row LayerNorm for ln0/ln1/shared slices of H, in place
// ---------------------------------------------------------------------------
__global__ __launch_bounds__(128) void k_ln(unsigned short* __restrict__ H,
    const float* __restrict__ ln_g, const float* __restrict__ ln_be,
    const float* __restrict__ sh_g, const float* __restrict__ sh_be){
  const int row = blockIdx.x, sl = blockIdx.y;
  unsigned short* p = H + (size_t)row * 7168 + 4096 + sl * 1024;
  const int t = threadIdx.x, lane = t & 63, w = t >> 6;
  short8v raw = *(const short8v*)&p[t * 8];
  float v[8]; float s = 0.f, s2 = 0.f;
  #pragma unroll
  for (int j = 0; j < 8; j++){ v[j] = bf2f((unsigned short)raw[j]); s += v[j]; s2 += v[j]*v[j]; }
  #pragma unroll
  for (int d = 1; d < 64; d <<= 1){ s += __shfl_xor(s, d); s2 += __shfl_xor(s2, d); }
  __shared__ float red[4];
  if (lane == 0){ red[w*2] = s; red[w*2+1] = s2; }
  __syncthreads();
  float ts = red[0] + red[2], tq = red[1] + red[3];
  float m   = ts * (1.f / 1024.f);
  float var = tq * (1.f / 1024.f) - m*m;
  float inv = 1.f / sqrtf(var + 1e-5f);
  const float* gp = (sl == 0) ? ln_g : (sl == 1) ? ln_g + 1024 : sh_g;
  const float* bp = (sl == 0) ? ln_be : (sl == 1) ? ln_be + 1024 : sh_be;
  short8v outv;
  #pragma unroll
  for (int j = 0; j < 8; j++){
    int cc = t*8 + j;
    outv[j] = (short)f2bf((v[j] - m) * inv * gp[cc] + bp[cc]);
  }
  *(short8v*)&p[t * 8] = outv;
}

// ---------------------------------------------------------------------------
// private = sum_e wgt[b][e] * expert_out[e][b,:]
// ---------------------------------------------------------------------------
__global__ __launch_bounds__(256) void k_combine(const unsigned short* __restrict__ eolin,
    const unsigned short* __restrict__ eoc, const float* __restrict__ wgt, float* __restrict__ priv){
  const int i = blockIdx.x * 256 + threadIdx.x;  // 524288
  const int b = i >> 7;
  const int c = (i & 127) * 8;
  const float* w = wgt + (size_t)b * 8;
  float acc[8];
  #pragma unroll
  for (int j = 0; j < 8; j++) acc[j] = 0.f;
  const int emap[6] = {0, 1, 2, 3, 6, 7};
  #pragma unroll
  for (int r = 0; r < 6; r++){
    float we = w[emap[r]];
    short8v v = *(const short8v*)&eolin[((size_t)r * NB + b) * 1024 + c];
    #pragma unroll
    for (int j = 0; j < 8; j++) acc[j] += we * bf2f((unsigned short)v[j]);
  }
  #pragma unroll
  for (int e2 = 0; e2 < 2; e2++){
    float we = w[4 + e2];
    short8v v = *(const short8v*)&eoc[((size_t)e2 * NB + b) * 1024 + c];
    #pragma unroll
    for (int j = 0; j < 8; j++) acc[j] += we * bf2f((unsigned short)v[j]);
  }
  float4v o0 = {acc[0], acc[1], acc[2], acc[3]};
  float4v o1 = {acc[4], acc[5], acc[6], acc[7]};
  float4v* dst = (float4v*)&priv[(size_t)b * 1024 + c];
  dst[0] = o0; dst[1] = o1;
}

// ---------------------------------------------------------------------------
// Host launch
// ---------------------------------------------------------------------------
extern "C" void kernel_launch(void* const* d_in, const int* in_sizes, int n_in,
                              void* d_out, int out_size, void* d_ws, size_t ws_size,
                              hipStream_t stream){
  const float* x      = (const float*)d_in[0];
  const int*   modal  = (const int*)d_in[1];
  const float* mlp_W1 = (const float*)d_in[2];
  const float* mlp_b1 = (const float*)d_in[3];
  const float* mlp_W2 = (const float*)d_in[4];
  const float* mlp_b2 = (const float*)d_in[5];
  const float* bn_W1  = (const float*)d_in[6];
  const float* bn_b1  = (const float*)d_in[7];
  const float* bn_g   = (const float*)d_in[8];
  const float* bn_be  = (const float*)d_in[9];
  const float* bn_W2  = (const float*)d_in[10];
  const float* bn_b2  = (const float*)d_in[11];
  const float* conv_k = (const float*)d_in[12];
  const float* conv_b = (const float*)d_in[13];
  const float* conv_W = (const float*)d_in[14];
  const float* conv_bL= (const float*)d_in[15];
  const float* ln_W1  = (const float*)d_in[16];
  const float* ln_b1  = (const float*)d_in[17];
  const float* ln_g   = (const float*)d_in[18];
  const float* ln_be  = (const float*)d_in[19];
  const float* ln_W2  = (const float*)d_in[20];
  const float* ln_b2  = (const float*)d_in[21];
  const float* sh_W1  = (const float*)d_in[22];
  const float* sh_b1  = (const float*)d_in[23];
  const float* sh_g   = (const float*)d_in[24];
  const float* sh_be  = (const float*)d_in[25];
  const float* sh_W2  = (const float*)d_in[26];
  const float* sh_b2  = (const float*)d_in[27];
  const float* g_W1   = (const float*)d_in[28];
  const float* g_b1   = (const float*)d_in[29];
  const float* g_W2   = (const float*)d_in[30];
  const float* g_b2   = (const float*)d_in[31];

  char* ws = (char*)d_ws;
  size_t o_xb   = 0;
  size_t o_xlo  = o_xb  + 8388608ull;
  size_t o_W1t  = o_xlo + 8388608ull;    // [9216][1024] bf16
  size_t o_W2t  = o_W1t + 18874368ull;   // [7168][1024] bf16
  size_t o_Wg   = o_W2t + 14680064ull;   // [512][3072] bf16
  size_t o_T    = o_Wg  + 3145728ull;    // [4096][512] f32 (gate raw)
  size_t o_H    = o_T   + 8388608ull;    // [4096][7168] bf16
  size_t o_eoc  = o_H   + 58720256ull;   // [2][4096][1024] bf16
  size_t o_eol  = o_eoc + 16777216ull;   // [6][4096][1024] bf16
  size_t o_b1   = o_eol + 50331648ull;   // [9216] f32
  size_t o_b2   = o_b1  + 36864ull;      // [7168] f32
  size_t o_wgt  = o_b2  + 28672ull;      // [4096][8] f32
  size_t o_ut   = o_wgt + 131072ull;     // [4096][8] f32 usage probs
  size_t o_scp  = o_ut  + 131072ull;     // [2][4][1024] f32 conv colsum partials
  size_t o_cst  = o_scp + 32768ull;      // [2][2048] f32 bn colstats

  unsigned short* xb    = (unsigned short*)(ws + o_xb);
  unsigned short* xlo   = (unsigned short*)(ws + o_xlo);
  unsigned short* W1t   = (unsigned short*)(ws + o_W1t);
  unsigned short* W2t   = (unsigned short*)(ws + o_W2t);
  unsigned short* Wg3t  = (unsigned short*)(ws + o_Wg);
  float*          T     = (float*)(ws + o_T);
  unsigned short* H     = (unsigned short*)(ws + o_H);
  unsigned short* eoc   = (unsigned short*)(ws + o_eoc);
  unsigned short* eolin = (unsigned short*)(ws + o_eol);
  float*          b1cat = (float*)(ws + o_b1);
  float*          b2cat = (float*)(ws + o_b2);
  float*          wgt   = (float*)(ws + o_wgt);
  float*          usageTok = (float*)(ws + o_ut);
  float*          scPart   = (float*)(ws + o_scp);
  float*          colstats = (float*)(ws + o_cst);

  float* outF   = (float*)d_out;
  float* shared = outF;                       // [4096][1024]
  float* priv   = outF + (size_t)NB * 1024;   // [4096][1024]
  float* auxp   = outF + (size_t)2 * NB * 1024; // [1]

  hipMemsetAsync(scPart, 0, 32768, stream);
  hipMemsetAsync(colstats, 0, 16384, stream);

  k_cast_x<<<4096, 256, 0, stream>>>(x, xb, xlo);

  TpArgs tp;
  for (int e = 0; e < 2; e++){
    tp.src[0 + e] = mlp_W1 + (size_t)e * 1048576;
    tp.src[2 + e] = bn_W1  + (size_t)e * 1048576;
    tp.src[4 + e] = ln_W1  + (size_t)e * 1048576;
  }
  tp.src[6] = sh_W1;
  for (int e = 0; e < 2; e++){
    tp.src[7 + e]  = mlp_W2 + (size_t)e * 1048576;
    tp.src[9 + e]  = bn_W2  + (size_t)e * 1048576;
    tp.src[11 + e] = ln_W2  + (size_t)e * 1048576;
  }
  tp.src[13] = sh_W2;
  for (int s = 0; s < 7; s++)  tp.dst[s] = W1t + (size_t)s * 1048576;
  for (int s = 7; s < 14; s++) tp.dst[s] = W2t + (size_t)(s - 7) * 1048576;
  k_transpose<<<dim3(32, 32, 14), dim3(32, 8), 0, stream>>>(tp);

  k_gateW<<<dim3(32, 16), dim3(32, 8), 0, stream>>>(g_W1, Wg3t);
  k_convW<<<dim3(4, 32, 2), 256, 0, stream>>>(conv_k, conv_W, W1t, scPart);
  k_biases<<<64, 256, 0, stream>>>(mlp_b1, bn_b1, ln_b1, sh_b1,
                                   mlp_b2, bn_b2, ln_b2, sh_b2,
                                   conv_b, conv_bL, scPart, b1cat, b2cat);

  // ---- fused layer 1 + gate GEMM1: one dispatch (gate tiles first) ----
  GemmArgs g1 = {};
  g1.A = xb; g1.A2 = xlo; g1.Bt = W1t; g1.Bt2 = Wg3t;
  g1.lda = 1024; g1.K = 1024;
  g1.bias = b1cat; g1.H = H; g1.eoc = eoc; g1.T = T;
  k_gemm128<0><<<dim3(2432), 256, 0, stream>>>(g1);

  k_bn_stats<<<64, 256, 0, stream>>>(H, colstats);
  k_bn_apply<<<256, 256, 0, stream>>>(H, colstats, bn_g, bn_be);
  k_ln<<<dim3(4096, 3), 128, 0, stream>>>(H, ln_g, ln_be, sh_g, sh_be);

  k_gate_fin<<<1024, 256, 0, stream>>>(T, g_W2, g_b2, g_b1, g_W1 + (size_t)1024 * 512,
                                       modal, wgt, usageTok);
  k_aux<<<1, 256, 0, stream>>>(usageTok, auxp);

  // ---- fused layer 2 (6 private experts + shared) ----
  GemmArgs g2 = {};
  g2.A = H; g2.Bt = W2t; g2.lda = 7168; g2.K = 1024;
  g2.bias = b2cat; g2.eolin = eolin; g2.outsh = shared;
  k_gemm128<1><<<dim3(1792), 256, 0, stream>>>(g2);

  k_combine<<<2048, 256, 0, stream>>>(eolin, eoc, wgt, priv);
}